// Round 13
// baseline (641.015 us; speedup 1.0000x reference)
//
#include <hip/hip_runtime.h>
#include <hip/hip_bf16.h>
#include <cstddef>
#include <cstdint>

#define D_MODEL     1024
#define D_INNER     2048
#define D_STATE     128
#define NHEADS      16
#define HEADDIM     128
#define D_CONV      4
#define CHUNK       256
#define CONV_DIM    2304      // D_INNER + 2*D_STATE
#define DIM_IN_PROJ 4368      // 2*D_INNER + 2*D_STATE + NHEADS
#define NPAD_WIN    4608      // 18*256 = 36*128, zero-padded W_in rows
#define BATCH       2
#define SEQ         4096
#define ROWS        8192      // BATCH*SEQ
#define NC          16        // SEQ/CHUNK
#define EPS         1e-5f

typedef __hip_bfloat16 bf16;
typedef __attribute__((ext_vector_type(8))) short bf16x8;
typedef __attribute__((ext_vector_type(4))) float f32x4;

__device__ __forceinline__ float sigmoidf_(float x) { return 1.f / (1.f + expf(-x)); }

__device__ __forceinline__ float ldf(const float* p) { return *p; }
__device__ __forceinline__ float ldf(const bf16* p)  { return __bfloat162float(*p); }
__device__ __forceinline__ void  stf(float* p, float v) { *p = v; }
__device__ __forceinline__ void  stf(bf16* p, float v)  { *p = __float2bfloat16(v); }

__device__ __forceinline__ short f2bs(float x) {
    bf16 h = __float2bfloat16(x);
    return __builtin_bit_cast(short, h);
}
__device__ __forceinline__ float bs2f(short s) {
    unsigned int u = ((unsigned int)(unsigned short)s) << 16;
    return __builtin_bit_cast(float, u);
}

#define GLOAD_LDS16(gp, lp) \
    __builtin_amdgcn_global_load_lds((const __attribute__((address_space(1))) unsigned int*)(gp), \
        (__attribute__((address_space(3))) unsigned int*)(lp), 16, 0, 0)

// ===========================================================================
// 128x256 bf16 GEMM: C = A[M][K] * B[N][K]^T — 3 blocks/CU occupancy variant
// 256 threads = 4 column-waves; each wave owns 128x64 output (acc[8][4]).
// BK=32; LDS = [2buf](A:128x32 + B:256x32) = 48 KB -> 3 blocks/CU (144<=160);
// VGPR 104 -> 3 waves/SIMD OK. Per K-tile: VMW0 (drains stage(t), issued one
// full phase earlier) -> BAR (publish) -> 12 ds_read -> stage(t+1) into buf^1
// (safe: prior readers done at BAR) -> 32 MFMA. Cross-block overlap (3/CU)
// hides the rendezvous.
// Grid: (M/128)*(N/256), %8==0 for bijective XCD swizzle.
// Requires: M%128==0, K%32==0, B rows valid up to col0+255 (pad B).
// ===========================================================================
__global__ __launch_bounds__(256, 3) void gemm128x256_mfma_bt(
    const bf16* __restrict__ A, const bf16* __restrict__ B, bf16* __restrict__ C,
    int M, int N, int K, int lda, int ldb, int ldc, int gx)
{
    __shared__ bf16 As[2][128 * 32];   // 16 KB
    __shared__ bf16 Bs[2][256 * 32];   // 32 KB

    const int tid  = threadIdx.x;
    const int lane = tid & 63;
    const int wave = tid >> 6;           // 0..3 : column quarter
    const int l15  = lane & 15;
    const int l4   = lane >> 4;

    // bijective XCD-chunked swizzle (grid % 8 == 0)
    const int cpx  = (int)gridDim.x >> 3;
    const int wg   = ((int)blockIdx.x & 7) * cpx + ((int)blockIdx.x >> 3);
    const int row0 = (wg / gx) * 128;
    const int col0 = (wg % gx) * 256;

    const int NT = K >> 5;

    f32x4 acc[8][4];
#pragma unroll
    for (int m = 0; m < 8; m++)
#pragma unroll
        for (int n = 0; n < 4; n++) acc[m][n] = (f32x4){0.f, 0.f, 0.f, 0.f};

#define BAR_()  { asm volatile("" ::: "memory"); __builtin_amdgcn_s_barrier(); asm volatile("" ::: "memory"); }
#define VMW0_() asm volatile("s_waitcnt vmcnt(0)" ::: "memory")

    auto STAGE_A = [&](int kt, int buf) {
#pragma unroll
        for (int sw = 0; sw < 2; sw++) {
            int s  = sw * 256 + tid;             // 0..511
            int r  = s >> 2;                     // 0..127
            int cg = (s & 3) ^ ((r >> 1) & 3);   // source pre-swizzle
            const bf16* src = A + (size_t)(row0 + r) * lda + kt * 32 + cg * 8;
            GLOAD_LDS16(src, &As[buf][s * 8]);   // linear dest
        }
    };
    auto STAGE_B = [&](int kt, int buf) {
#pragma unroll
        for (int sw = 0; sw < 4; sw++) {
            int s  = sw * 256 + tid;             // 0..1023
            int r  = s >> 2;                     // 0..255
            int cg = (s & 3) ^ ((r >> 1) & 3);
            const bf16* src = B + (size_t)(col0 + r) * ldb + kt * 32 + cg * 8;
            GLOAD_LDS16(src, &Bs[buf][s * 8]);
        }
    };
    auto LOADA = [&](int buf, bf16x8* af) {
#pragma unroll
        for (int i = 0; i < 8; i++) {
            int r = i * 16 + l15;
            af[i] = *reinterpret_cast<const bf16x8*>(
                &As[buf][r * 32 + ((l4 ^ ((r >> 1) & 3)) << 3)]);
        }
    };
    auto LOADB = [&](int buf, bf16x8* bb) {
#pragma unroll
        for (int n = 0; n < 4; n++) {
            int r = wave * 64 + n * 16 + l15;
            bb[n] = *reinterpret_cast<const bf16x8*>(
                &Bs[buf][r * 32 + ((l4 ^ ((r >> 1) & 3)) << 3)]);
        }
    };
    auto MFMAQ = [&](bf16x8* af, bf16x8* bb) {
        __builtin_amdgcn_s_setprio(1);
#pragma unroll
        for (int i = 0; i < 8; i++)
#pragma unroll
            for (int n = 0; n < 4; n++)
                acc[i][n] = __builtin_amdgcn_mfma_f32_16x16x32_bf16(
                    af[i], bb[n], acc[i][n], 0, 0, 0);
        __builtin_amdgcn_s_setprio(0);
    };

    // prologue: stage tile 0 fully
    STAGE_A(0, 0); STAGE_B(0, 0);

    bf16x8 af[8], bb[4];
    for (int t = 0; t < NT; t++) {
        const int buf = t & 1;
        VMW0_();                 // drain stage(t) (issued a full phase ago)
        BAR_();                  // publish to all waves
        LOADA(buf, af);
        LOADB(buf, bb);
        if (t + 1 < NT) {        // stage next tile into the opposite buffer
            STAGE_A(t + 1, buf ^ 1);
            STAGE_B(t + 1, buf ^ 1);
        }
        MFMAQ(af, bb);
    }

    // epilogue
#pragma unroll
    for (int m = 0; m < 8; m++) {
        int gr = row0 + m * 16 + l4 * 4;
#pragma unroll
        for (int n = 0; n < 4; n++) {
            int gc = col0 + wave * 64 + n * 16 + l15;
            if (gc < N) {
#pragma unroll
                for (int j = 0; j < 4; j++)
                    stf(&C[(size_t)(gr + j) * ldc + gc], acc[m][n][j]);
            }
        }
    }
#undef BAR_
#undef VMW0_
}

// ===========================================================================
// 128x128 bf16 GEMM: counted-vmcnt kk-split (best for the skinny out-proj)
// ===========================================================================
template<typename TC>
__global__ __launch_bounds__(256, 2) void gemm128c_mfma_bt(
    const bf16* __restrict__ A, const bf16* __restrict__ B, TC* __restrict__ C,
    int M, int N, int K, int lda, int ldb, int ldc, int gx)
{
    __shared__ bf16 As[2][2][128 * 32];
    __shared__ bf16 Bs[2][2][128 * 32];

    const int tid  = threadIdx.x;
    const int lane = tid & 63;
    const int wave = tid >> 6;
    const int wm   = wave >> 1;
    const int wn   = wave & 1;
    const int l15  = lane & 15;
    const int l4   = lane >> 4;

    const int cpx  = (int)gridDim.x >> 3;
    const int wg   = ((int)blockIdx.x & 7) * cpx + ((int)blockIdx.x >> 3);
    const int row0 = (wg / gx) * 128;
    const int col0 = (wg % gx) * 128;

    const int NT = K >> 6;

    f32x4 acc[4][4];
#pragma unroll
    for (int m = 0; m < 4; m++)
#pragma unroll
        for (int n = 0; n < 4; n++) acc[m][n] = (f32x4){0.f, 0.f, 0.f, 0.f};

#define BAR_()  { asm volatile("" ::: "memory"); __builtin_amdgcn_s_barrier(); asm volatile("" ::: "memory"); }
#define VMW0_() asm volatile("s_waitcnt vmcnt(0)" ::: "memory")
#define VMW4_() asm volatile("s_waitcnt vmcnt(4)" ::: "memory")

    auto STAGE_A = [&](int kt, int buf, int kk) {
#pragma unroll
        for (int sw = 0; sw < 2; sw++) {
            int s  = sw * 256 + tid;
            int r  = s >> 2;
            int cg = (s & 3) ^ ((r >> 1) & 3);
            const bf16* src = A + (size_t)(row0 + r) * lda + kt * 64 + kk * 32 + cg * 8;
            GLOAD_LDS16(src, &As[buf][kk][s * 8]);
        }
    };
    auto STAGE_B = [&](int kt, int buf, int kk) {
#pragma unroll
        for (int sw = 0; sw < 2; sw++) {
            int s  = sw * 256 + tid;
            int r  = s >> 2;
            int cg = (s & 3) ^ ((r >> 1) & 3);
            const bf16* src = B + (size_t)(col0 + r) * ldb + kt * 64 + kk * 32 + cg * 8;
            GLOAD_LDS16(src, &Bs[buf][kk][s * 8]);
        }
    };
    auto LOADA = [&](int buf, int kk, bf16x8* af) {
#pragma unroll
        for (int i = 0; i < 4; i++) {
            int r = wm * 64 + i * 16 + l15;
            af[i] = *reinterpret_cast<const bf16x8*>(
                &As[buf][kk][r * 32 + ((l4 ^ ((r >> 1) & 3)) << 3)]);
        }
    };
    auto LOADB = [&](int buf, int kk, bf16x8* bb) {
#pragma unroll
        for (int n = 0; n < 4; n++) {
            int r = wn * 64 + n * 16 + l15;
            bb[n] = *reinterpret_cast<const bf16x8*>(
                &Bs[buf][kk][r * 32 + ((l4 ^ ((r >> 1) & 3)) << 3)]);
        }
    };
    auto MFMAQ = [&](bf16x8* af, bf16x8* bb) {
        __builtin_amdgcn_s_setprio(1);
#pragma unroll
        for (int i = 0; i < 4; i++)
#pragma unroll
            for (int n = 0; n < 4; n++)
                acc[i][n] = __builtin_amdgcn_mfma_f32_16x16x32_bf16(
                    af[i], bb[n], acc[i][n], 0, 0, 0);
        __builtin_amdgcn_s_setprio(0);
    };

    STAGE_A(0, 0, 0); STAGE_B(0, 0, 0);
    STAGE_A(0, 0, 1); STAGE_B(0, 0, 1);
    VMW0_();
    BAR_();

    bf16x8 af[4], bb[4];
    for (int t = 0; t < NT; t++) {
        const int buf  = t & 1;
        const int nbuf = buf ^ 1;
        const int nk   = (t + 1 < NT) ? t + 1 : 0;
        LOADA(buf, 0, af);
        LOADB(buf, 0, bb);
        STAGE_A(nk, nbuf, 0);
        STAGE_B(nk, nbuf, 0);
        VMW4_();
        BAR_();
        MFMAQ(af, bb);
        LOADA(buf, 1, af);
        LOADB(buf, 1, bb);
        STAGE_A(nk, nbuf, 1);
        STAGE_B(nk, nbuf, 1);
        VMW4_();
        BAR_();
        MFMAQ(af, bb);
    }

#pragma unroll
    for (int m = 0; m < 4; m++) {
        int gr = row0 + wm * 64 + m * 16 + l4 * 4;
#pragma unroll
        for (int n = 0; n < 4; n++) {
            int gc = col0 + wn * 64 + n * 16 + l15;
            if (gc < N) {
#pragma unroll
                for (int j = 0; j < 4; j++)
                    stf(&C[(size_t)(gr + j) * ldc + gc], acc[m][n][j]);
            }
        }
    }
#undef BAR_
#undef VMW0_
#undef VMW4_
}

// ---------------------------------------------------------------------------
// MFMA bf16 GEMM (m97 structure) — kept for the batched CB GEMM
// ---------------------------------------------------------------------------
template<typename TC>
__global__ __launch_bounds__(256) void gemm_mfma_bt(
    const bf16* __restrict__ A, const bf16* __restrict__ B, TC* __restrict__ C,
    int M, int N, int K, int lda, int ldb, int ldc,
    long long sA, long long sB, long long sC)
{
    A += (long long)blockIdx.z * sA;
    B += (long long)blockIdx.z * sB;
    C += (long long)blockIdx.z * sC;

    __shared__ bf16 As[128 * 32];
    __shared__ bf16 Bs[128 * 32];

    const int tid  = threadIdx.x;
    const int lane = tid & 63;
    const int wave = tid >> 6;
    const int wr   = wave >> 1;
    const int wc   = wave & 1;
    const int row0 = blockIdx.y * 128;
    const int col0 = blockIdx.x * 128;
    const int l15  = lane & 15;
    const int l4   = lane >> 4;

    const int srow = tid >> 2;
    const int scol = (tid & 3) * 8;

    f32x4 acc[4][4];
#pragma unroll
    for (int m = 0; m < 4; m++)
#pragma unroll
        for (int n = 0; n < 4; n++) acc[m][n] = (f32x4){0.f, 0.f, 0.f, 0.f};

    for (int k0 = 0; k0 < K; k0 += 32) {
        const bf16* gA0 = A + (size_t)(row0 + srow) * lda + k0 + scol;
        const bf16* gA1 = A + (size_t)(row0 + 64 + srow) * lda + k0 + scol;
        const bf16* gB0 = B + (size_t)(col0 + srow) * ldb + k0 + scol;
        const bf16* gB1 = B + (size_t)(col0 + 64 + srow) * ldb + k0 + scol;
        GLOAD_LDS16(gA0, &As[tid * 8]);
        GLOAD_LDS16(gA1, &As[2048 + tid * 8]);
        GLOAD_LDS16(gB0, &Bs[tid * 8]);
        GLOAD_LDS16(gB1, &Bs[2048 + tid * 8]);
        __syncthreads();

        bf16x8 af[4], bg[4];
#pragma unroll
        for (int m = 0; m < 4; m++) {
            int r = wr * 64 + m * 16 + l15;
            af[m] = *reinterpret_cast<const bf16x8*>(&As[r * 32 + l4 * 8]);
        }
#pragma unroll
        for (int n = 0; n < 4; n++) {
            int r = wc * 64 + n * 16 + l15;
            bg[n] = *reinterpret_cast<const bf16x8*>(&Bs[r * 32 + l4 * 8]);
        }
#pragma unroll
        for (int m = 0; m < 4; m++)
#pragma unroll
            for (int n = 0; n < 4; n++)
                acc[m][n] = __builtin_amdgcn_mfma_f32_16x16x32_bf16(af[m], bg[n], acc[m][n], 0, 0, 0);
        __syncthreads();
    }

#pragma unroll
    for (int m = 0; m < 4; m++) {
        int grb = row0 + wr * 64 + m * 16 + l4 * 4;
#pragma unroll
        for (int n = 0; n < 4; n++) {
            int gc = col0 + wc * 64 + n * 16 + l15;
            if (gc < N) {
#pragma unroll
                for (int j = 0; j < 4; j++) {
                    int gr = grb + j;
                    if (gr < M) stf(&C[(size_t)gr * ldc + gc], acc[m][n][j]);
                }
            }
        }
    }
}

// ---------------------------------------------------------------------------
// dt projection + softplus + bf16 cast of u, fused. One wave per row.
// ---------------------------------------------------------------------------
__global__ __launch_bounds__(256) void dt_proj_kernel(
    const float* __restrict__ u, const float* __restrict__ Wdt,
    const float* __restrict__ dt_bias, float* __restrict__ dtsp,
    ushort* __restrict__ ub)
{
    const int wave = threadIdx.x >> 6;
    const int lane = threadIdx.x & 63;
    const int row  = blockIdx.x * 4 + wave;
    const float* urow = u + (size_t)row * D_MODEL;

    float4 uv[4];
#pragma unroll
    for (int w = 0; w < 4; w++)
        uv[w] = *reinterpret_cast<const float4*>(&urow[lane * 4 + w * 256]);

#pragma unroll
    for (int w = 0; w < 4; w++) {
        ushort4 o;
        o.x = (unsigned short)f2bs(uv[w].x);
        o.y = (unsigned short)f2bs(uv[w].y);
        o.z = (unsigned short)f2bs(uv[w].z);
        o.w = (unsigned short)f2bs(uv[w].w);
        *reinterpret_cast<ushort4*>(&ub[(size_t)row * D_MODEL + lane * 4 + w * 256]) = o;
    }

    float acc[NHEADS];
#pragma unroll
    for (int h = 0; h < NHEADS; h++) acc[h] = 0.f;
#pragma unroll
    for (int w = 0; w < 4; w++) {
#pragma unroll
        for (int h = 0; h < NHEADS; h++) {
            float4 wv = *reinterpret_cast<const float4*>(&Wdt[(size_t)h * D_MODEL + lane * 4 + w * 256]);
            acc[h] += uv[w].x * wv.x + uv[w].y * wv.y + uv[w].z * wv.z + uv[w].w * wv.w;
        }
    }
#pragma unroll
    for (int h = 0; h < NHEADS; h++)
#pragma unroll
        for (int off = 32; off > 0; off >>= 1)
            acc[h] += __shfl_xor(acc[h], off, 64);

    float sel = 0.f;
#pragma unroll
    for (int h = 0; h < NHEADS; h++) sel = (lane == h) ? acc[h] : sel;
    if (lane < NHEADS) {
        float x = sel + dt_bias[lane];
        dtsp[(size_t)row * NHEADS + lane] = (x > 20.f) ? x : log1pf(expf(x));
    }
}

// ---------------------------------------------------------------------------
// casts (weights)
// ---------------------------------------------------------------------------
__global__ __launch_bounds__(256) void cast_bf16_kernel(
    const float4* __restrict__ src, ushort4* __restrict__ dst, int n4)
{
    int i = blockIdx.x * 256 + threadIdx.x;
    if (i >= n4) return;
    float4 v = src[i];
    ushort4 o;
    o.x = (unsigned short)f2bs(v.x);
    o.y = (unsigned short)f2bs(v.y);
    o.z = (unsigned short)f2bs(v.z);
    o.w = (unsigned short)f2bs(v.w);
    dst[i] = o;
}

__global__ __launch_bounds__(256) void cast_win_kernel(
    const float4* __restrict__ src, ushort4* __restrict__ dst)
{
    int i = blockIdx.x * 256 + threadIdx.x;
    if (i >= NPAD_WIN * D_MODEL / 4) return;
    int row = (i * 4) / D_MODEL;
    ushort4 o = {0, 0, 0, 0};
    if (row < DIM_IN_PROJ) {
        float4 v = src[i];
        o.x = (unsigned short)f2bs(v.x);
        o.y = (unsigned short)f2bs(v.y);
        o.z = (unsigned short)f2bs(v.z);
        o.w = (unsigned short)f2bs(v.w);
    }
    dst[i] = o;
}

// ---------------------------------------------------------------------------
// Depthwise causal conv (width 4) + bias + SiLU — register halo reuse:
// each thread computes 4 consecutive rows x 8 channels from 7 row-vectors.
// ---------------------------------------------------------------------------
__global__ __launch_bounds__(256) void conv_silu_kernel(
    const bf16* __restrict__ zx, const float* __restrict__ cw,
    const float* __restrict__ cb, bf16* __restrict__ xbc)
{
    const int CW = CONV_DIM / 8;               // 288
    int idx = blockIdx.x * 256 + threadIdx.x;  // over (ROWS/4) * CW
    if (idx >= (ROWS / 4) * CW) return;
    int c8   = idx % CW;
    int r4   = idx / CW;
    int c0   = c8 * 8;
    int row0 = r4 * 4;
    int l0   = row0 & (SEQ - 1);

    float vr[7][8];
#pragma unroll
    for (int k = 0; k < 7; k++) {
        int ls = l0 - 3 + k;
        if (ls < 0) {
#pragma unroll
            for (int j = 0; j < 8; j++) vr[k][j] = 0.f;
        } else {
            bf16x8 v = *reinterpret_cast<const bf16x8*>(
                zx + (size_t)(row0 - 3 + k) * DIM_IN_PROJ + D_INNER + c0);
#pragma unroll
            for (int j = 0; j < 8; j++) vr[k][j] = bs2f(v[j]);
        }
    }

    float4 t[8];
#pragma unroll
    for (int j = 0; j < 8; j++)
        t[j] = *reinterpret_cast<const float4*>(&cw[(size_t)(c0 + j) * D_CONV]);
    float bias[8];
    {
        float4 b0 = *reinterpret_cast<const float4*>(&cb[c0]);
        float4 b1 = *reinterpret_cast<const float4*>(&cb[c0 + 4]);
        bias[0] = b0.x; bias[1] = b0.y; bias[2] = b0.z; bias[3] = b0.w;
        bias[4] = b1.x; bias[5] = b1.y; bias[6] = b1.z; bias[7] = b1.w;
    }

#pragma unroll
    for (int r = 0; r < 4; r++) {
        float acc[8];
#pragma unroll
        for (int j = 0; j < 8; j++) acc[j] = bias[j];
#pragma unroll
        for (int k = 0; k < D_CONV; k++) {
#pragma unroll
            for (int j = 0; j < 8; j++) {
                float tap = (k == 0) ? t[j].x : (k == 1) ? t[j].y : (k == 2) ? t[j].z : t[j].w;
                acc[j] += tap * vr[r + k][j];
            }
        }
        bf16x8 o;
#pragma unroll
        for (int j = 0; j < 8; j++) {
            float x = acc[j];
            o[j] = f2bs(x * sigmoidf_(x));
        }
        *reinterpret_cast<bf16x8*>(&xbc[(size_t)(row0 + r) * CONV_DIM + c0]) = o;
    }
}

// ---------------------------------------------------------------------------
__global__ __launch_bounds__(256) void cumsum_kernel(
    const float* __restrict__ dtsp, const float* __restrict__ A_log,
    float* __restrict__ Acs)
{
    int blk = blockIdx.x;
    int h   = blk % NHEADS;
    int bc  = blk / NHEADS;
    int t   = threadIdx.x;
    int row = bc * CHUNK + t;
    float A = -expf(A_log[h]);
    __shared__ float buf[CHUNK];
    buf[t] = dtsp[(size_t)row * NHEADS + h] * A;
    __syncthreads();
    for (int off = 1; off < CHUNK; off <<= 1) {
        float v = (t >= off) ? buf[t - off] : 0.f;
        __syncthreads();
        buf[t] += v;
        __syncthreads();
    }
    Acs[(size_t)blk * CHUNK + t] = buf[t];
}

// ---------------------------------------------------------------------------
// states (MFMA): states[p][n] = sum_q xg[q,p] * B[q,n]
// ---------------------------------------------------------------------------
__global__ __launch_bounds__(256, 2) void states_mfma_kernel(
    const bf16* __restrict__ xbc, const float* __restrict__ dtsp,
    const float* __restrict__ Acs, float* __restrict__ states)
{
    const int bch  = blockIdx.x;
    const int h    = bch % NHEADS;
    const int bc   = bch / NHEADS;
    const int row0 = bc * CHUNK;
    const int tid  = threadIdx.x;
    const int lane = tid & 63;
    const int wave = tid >> 6;
    const int l15  = lane & 15;
    const int l4   = lane >> 4;

    __shared__ float g[CHUNK];
    __shared__ bf16 xT[128 * 32];
    __shared__ bf16 bT[128 * 32];

    {
        float last = Acs[(size_t)bch * CHUNK + CHUNK - 1];
        float a    = Acs[(size_t)bch * CHUNK + tid];
        g[tid] = dtsp[(size_t)(row0 + tid) * NHEADS + h] * __expf(last - a);
    }

    const int sp0 = (tid & 15) * 8;
    const int ssl = 2 * (tid >> 4);

    f32x4 acc[2][8];
#pragma unroll
    for (int m = 0; m < 2; m++)
#pragma unroll
        for (int n = 0; n < 8; n++) acc[m][n] = (f32x4){0.f, 0.f, 0.f, 0.f};

    for (int q0 = 0; q0 < CHUNK; q0 += 32) {
        __syncthreads();
        {
            const bf16* gx = xbc + (size_t)(row0 + q0 + ssl) * CONV_DIM + h * HEADDIM + sp0;
            bf16x8 v0 = *reinterpret_cast<const bf16x8*>(gx);
            bf16x8 v1 = *reinterpret_cast<const bf16x8*>(gx + CONV_DIM);
            const bf16* gb = xbc + (size_t)(row0 + q0 + ssl) * CONV_DIM + D_INNER + sp0;
            bf16x8 w0 = *reinterpret_cast<const bf16x8*>(gb);
            bf16x8 w1 = *reinterpret_cast<const bf16x8*>(gb + CONV_DIM);
            float g0 = g[q0 + ssl], g1 = g[q0 + ssl + 1];
#pragma unroll
            for (int j = 0; j < 8; j++) {
                unsigned int px = (unsigned short)f2bs(bs2f(v0[j]) * g0) |
                                  ((unsigned int)(unsigned short)f2bs(bs2f(v1[j]) * g1) << 16);
                *reinterpret_cast<unsigned int*>(&xT[(sp0 + j) * 32 + ssl]) = px;
                unsigned int pb = (unsigned short)w0[j] |
                                  ((unsigned int)(unsigned short)w1[j] << 16);
                *reinterpret_cast<unsigned int*>(&bT[(sp0 + j) * 32 + ssl]) = pb;
            }
        }
        __syncthreads();

        bf16x8 af[2], bg[8];
#pragma unroll
        for (int m = 0; m < 2; m++) {
            int p = wave * 32 + m * 16 + l15;
            af[m] = *reinterpret_cast<const bf16x8*>(&xT[p * 32 + l4 * 8]);
        }
#pragma unroll
        for (int n = 0; n < 8; n++) {
            int nn = n * 16 + l15;
            bg[n] = *reinterpret_cast<const bf16x8*>(&bT[nn * 32 + l4 * 8]);
        }
#pragma unroll
        for (int m = 0; m < 2; m++)
#pragma unroll
            for (int n = 0; n < 8; n++)
                acc[m][n] = __builtin_amdgcn_mfma_f32_16x16x32_bf16(af[m], bg[n], acc[m][n], 0, 0, 0);
    }

    float* sp = states + (size_t)bch * HEADDIM * D_STATE;
#pragma unroll
    for (int m = 0; m < 2; m++) {
        int pb = wave * 32 + m * 16 + l4 * 4;
#pragma unroll
        for (int n = 0; n < 8; n++) {
            int nn = n * 16 + l15;
#pragma unroll
            for (int j = 0; j < 4; j++)
                sp[(size_t)(pb + j) * D_STATE + nn] = acc[m][n][j];
        }
    }
}

// ---------------------------------------------------------------------------
// Sequential inter-chunk scan, IN PLACE on states
// ---------------------------------------------------------------------------
__global__ __launch_bounds__(256) void chunkscan_kernel(
    float* __restrict__ states, const float* __restrict__ Acs)
{
    int idx = blockIdx.x * 256 + threadIdx.x;
    int pn  = idx % (HEADDIM * D_STATE);
    int bh  = idx / (HEADDIM * D_STATE);
    int h   = bh % NHEADS;
    int b   = bh / NHEADS;
    float carry = 0.f;
    for (int c = 0; c < NC; c++) {
        int bch = (b * NC + c) * NHEADS + h;
        size_t off = (size_t)bch * HEADDIM * D_STATE + pn;
        float s   = states[off];
        states[off] = carry;
        float dec = expf(Acs[(size_t)bch * CHUNK + CHUNK - 1]);
        carry = carry * dec + s;
    }
}

// ---------------------------------------------------------------------------
// Y (MFMA): diag (causal, CB*L) + off (prev-state) per (b,c,h)
// ---------------------------------------------------------------------------
__global__ __launch_bounds__(256, 2) void y_mfma_kernel(
    const bf16* __restrict__ xbc, const float* __restrict__ dtsp,
    const float* __restrict__ Acs, const float* __restrict__ CBm,
    const float* __restrict__ prev, bf16* __restrict__ Y)
{
    const int bch  = blockIdx.x;
    const int h    = bch % NHEADS;
    const int bc   = bch / NHEADS;
    const int row0 = bc * CHUNK;
    const int tid  = threadIdx.x;
    const int lane = tid & 63;
    const int wave = tid >> 6;
    const int l15  = lane & 15;
    const int l4   = lane >> 4;

    __shared__ float sAcs[CHUNK];
    __shared__ float sdt[CHUNK];
    __shared__ bf16 xT[128 * 32];

    sAcs[tid] = Acs[(size_t)bch * CHUNK + tid];
    sdt[tid]  = dtsp[(size_t)(row0 + tid) * NHEADS + h];
    __syncthreads();

    int qb[4]; float aq[4];
#pragma unroll
    for (int m = 0; m < 4; m++) {
        qb[m] = (m * 4 + wave) * 16;
        aq[m] = sAcs[qb[m] + l15];
    }

    f32x4 acc[4][8];
#pragma unroll
    for (int m = 0; m < 4; m++)
#pragma unroll
        for (int n = 0; n < 8; n++) acc[m][n] = (f32x4){0.f, 0.f, 0.f, 0.f};

    const int sp0 = (tid & 15) * 8;
    const int ssl = 2 * (tid >> 4);

    // ---------------- diag phase ----------------
    for (int s0 = 0; s0 < CHUNK; s0 += 32) {
        __syncthreads();
        {
            const bf16* gx = xbc + (size_t)(row0 + s0 + ssl) * CONV_DIM + h * HEADDIM + sp0;
            bf16x8 v0 = *reinterpret_cast<const bf16x8*>(gx);
            bf16x8 v1 = *reinterpret_cast<const bf16x8*>(gx + CONV_DIM);
            float d0 = sdt[s0 + ssl], d1 = sdt[s0 + ssl + 1];
#pragma unroll
            for (int j = 0; j < 8; j++) {
                unsigned int px = (unsigned short)f2bs(bs2f(v0[j]) * d0) |
                                  ((unsigned int)(unsigned short)f2bs(bs2f(v1[j]) * d1) << 16);
                *reinterpret_cast<unsigned int*>(&xT[(sp0 + j) * 32 + ssl]) = px;
            }
        }
        __syncthreads();

        bf16x8 bg[8];
#pragma unroll
        for (int n = 0; n < 8; n++)
            bg[n] = *reinterpret_cast<const bf16x8*>(&xT[(n * 16 + l15) * 32 + l4 * 8]);

        f32x4 as0 = *reinterpret_cast<const f32x4*>(&sAcs[s0 + l4 * 8]);
        f32x4 as1 = *reinterpret_cast<const f32x4*>(&sAcs[s0 + l4 * 8 + 4]);

#pragma unroll
        for (int m = 0; m < 4; m++) {
            if (s0 >= qb[m] + 16) continue;
            int q = qb[m] + l15;
            const float* cbp = CBm + ((size_t)bc * CHUNK + q) * CHUNK + s0 + l4 * 8;
            f32x4 c0 = *reinterpret_cast<const f32x4*>(cbp);
            f32x4 c1 = *reinterpret_cast<const f32x4*>(cbp + 4);
            bf16x8 af;
#pragma unroll
            for (int j = 0; j < 8; j++) {
                int s = s0 + l4 * 8 + j;
                float cb = (j < 4) ? c0[j] : c1[j - 4];
                float a  = (j < 4) ? as0[j] : as1[j - 4];
                float w  = (s <= q) ? cb * __expf(aq[m] - a) : 0.f;
                af[j] = f2bs(w);
            }
#pragma unroll
            for (int n = 0; n < 8; n++)
                acc[m][n] = __builtin_amdgcn_mfma_f32_16x16x32_bf16(af, bg[n], acc[m][n], 0, 0, 0);
        }
    }

    // ---------------- off (prev-state) phase ----------------
    float eaq[4];
#pragma unroll
    for (int m = 0; m < 4; m++) eaq[m] = __expf(aq[m]);

    const float* prevh = prev + (size_t)bch * HEADDIM * D_STATE;
    for (int n0 = 0; n0 < D_STATE; n0 += 32) {
        bf16x8 bg[8];
#pragma unroll
        for (int n = 0; n < 8; n++) {
            const float* pr = prevh + (size_t)(n * 16 + l15) * D_STATE + n0 + l4 * 8;
            f32x4 u0 = *reinterpret_cast<const f32x4*>(pr);
            f32x4 u1 = *reinterpret_cast<const f32x4*>(pr + 4);
            bf16x8 b;
#pragma unroll
            for (int j = 0; j < 4; j++) { b[j] = f2bs(u0[j]); b[4 + j] = f2bs(u1[j]); }
            bg[n] = b;
        }
#pragma unroll
        for (int m = 0; m < 4; m++) {
            const bf16* crow = xbc + (size_t)(row0 + qb[m] + l15) * CONV_DIM
                             + D_INNER + D_STATE + n0 + l4 * 8;
            bf16x8 cv = *reinterpret_cast<const bf16x8*>(crow);
            bf16x8 af;
#pragma unroll
            for (int j = 0; j < 8; j++) af[j] = f2bs(bs2f(cv[j]) * eaq[m]);
#pragma unroll
            for (int n = 0; n < 8; n++)
                acc[m][n] = __builtin_amdgcn_mfma_f32_16x16x32_bf16(af, bg[n], acc[m][n], 0, 0, 0);
        }
    }

    // ---------------- write Y ----------------
#pragma unroll
    for (int m = 0; m < 4; m++) {
        int qrb = qb[m] + l4 * 4;
#pragma unroll
        for (int n = 0; n < 8; n++) {
            int p = n * 16 + l15;
#pragma unroll
            for (int j = 0; j < 4; j++)
                stf(&Y[(size_t)(row0 + qrb + j) * D_INNER + h * HEADDIM + p], acc[m][n][j]);
        }
    }
}

// ---------------------------------------------------------------------------
// y = (Y + D*x) * silu(z);  RMSNorm; in-place on Y (bf16) — vectorized
// ---------------------------------------------------------------------------
__global__ __launch_bounds__(256) void gate_norm_kernel(
    bf16* __restrict__ Yio, const bf16* __restrict__ zx,
    const bf16* __restrict__ xbc, const float* __restrict__ Dv,
    const float* __restrict__ nw)
{
    int row = blockIdx.x;
    int t   = threadIdx.x;
    int d0  = t * 8;

    bf16x8 yv = *reinterpret_cast<const bf16x8*>(&Yio[(size_t)row * D_INNER + d0]);
    bf16x8 xv = *reinterpret_cast<const bf16x8*>(&xbc[(size_t)row * CONV_DIM + d0]);
    bf16x8 zv = *reinterpret_cast<const bf16x8*>(&zx[(size_t)row * DIM_IN_PROJ + d0]);
    float Dh = Dv[d0 >> 7];

    float vals[8];
    float ss = 0.f;
#pragma unroll
    for (int j = 0; j < 8; j++) {
        float y = bs2f(yv[j]) + Dh * bs2f(xv[j]);
        float z = bs2f(zv[j]);
        y *= z * sigmoidf_(z);
        vals[j] = y;
        ss += y * y;
    }
    __shared__ float red[256];
    red[t] = ss;
    __syncthreads();
    for (int o = 128; o > 0; o >>= 1) {
        if (t < o) red[t] += red[t + o];
        __syncthreads();
    }
    float rms = rsqrtf(red[0] / (float)D_INNER + EPS);

    float4 w0 = *reinterpret_cast<const float4*>(&nw[d0]);
    float4 w1 = *reinterpret_cast<const float4*>(&nw[d0 + 4]);
    bf16x8 o;
    o[0] = f2bs(vals[0] * rms * w0.x);
    o[1] = f2bs(vals[1] * rms * w0.y);
    o[2] = f2bs(vals[2] * rms * w0.z);
    o[3] = f2bs(vals[3] * rms * w0.w);
    o[4] = f2bs(vals[4] * rms * w1.x);
    o[5] = f2bs(vals[5] * rms * w1.y);
    o[6] = f2bs(vals[6] * rms * w1.z);
    o[7] = f2bs(vals[7] * rms * w1.w);
    *reinterpret_cast<bf16x8*>(&Yio[(size_t)row * D_INNER + d0]) = o;
}

// ---------------------------------------------------------------------------
extern "C" void kernel_launch(void* const* d_in, const int* in_sizes, int n_in,
                              void* d_out, int out_size, void* d_ws, size_t ws_size,
                              hipStream_t stream)
{
    const float* u       = (const float*)d_in[0];
    const float* W_in    = (const float*)d_in[1];
    const float* conv_w  = (const float*)d_in[2];
    const float* conv_b  = (const float*)d_in[3];
    const float* dt_bias = (const float*)d_in[4];
    const float* A_log   = (const float*)d_in[5];
    const float* Dv      = (const float*)d_in[6];
    const float* norm_w  = (const float*)d_in[7];
    const float* W_out   = (const float*)d_in[8];
    float* out = (float*)d_out;

    char* base = (char*)d_ws;
    size_t off = 0;
    auto alloc = [&](size_t bytes) -> char* {
        char* p = base + off;
        off += (bytes + 255) & ~(size_t)255;
        return p;
    };
    bf16*  zxb    = (bf16*) alloc((size_t)ROWS * DIM_IN_PROJ * 2);                      // 71.5 MB
    bf16*  xbc    = (bf16*) alloc((size_t)ROWS * CONV_DIM * 2);                         // 37.7 MB
    float* dtsp   = (float*)alloc((size_t)ROWS * NHEADS * 4);
    float* Acs    = (float*)alloc((size_t)BATCH * NC * NHEADS * CHUNK * 4);
    float* states = (float*)alloc((size_t)BATCH * NC * NHEADS * HEADDIM * D_STATE * 4); // 33.5 MB
    float* CBm    = (float*)alloc((size_t)BATCH * NC * CHUNK * CHUNK * 4);              //  8.4 MB
    bf16*  Y      = (bf16*) alloc((size_t)ROWS * D_INNER * 2);                          // 33.5 MB
    bf16*  woutb  = (bf16*) alloc((size_t)D_MODEL * D_INNER * 2);                       //  4.2 MB
    bf16*  ub     = Y;                               // aliases: dead once y_mfma runs
    bf16*  winb   = Y + (size_t)ROWS * D_MODEL;      // 4608*1024 bf16 = 9.4 MB
    if (off > ws_size) return;

    // 0. dt projection (fp32) + softplus + u->bf16 cast, fused
    dt_proj_kernel<<<ROWS / 4, 256, 0, stream>>>(
        u, W_in + (size_t)(D_INNER + CONV_DIM) * D_MODEL, dt_bias, dtsp, (ushort*)ub);

    // 0b. weight casts
    cast_win_kernel<<<(NPAD_WIN * D_MODEL / 4 + 255) / 256, 256, 0, stream>>>(
        (const float4*)W_in, (ushort4*)winb);
    cast_bf16_kernel<<<(D_MODEL * D_INNER / 4 + 255) / 256, 256, 0, stream>>>(
        (const float4*)W_out, (ushort4*)woutb, D_MODEL * D_INNER / 4);

    // 1. in-projection: 128x256 3-blocks/CU MFMA (grid 64x18 = 1152, %8==0)
    gemm128x256_mfma_bt<<<(ROWS / 128) * (NPAD_WIN / 256), 256, 0, stream>>>(
        ub, winb, zxb, ROWS, DIM_IN_PROJ, D_MODEL,
        D_MODEL, D_MODEL, DIM_IN_PROJ, NPAD_WIN / 256);

    // 2. conv + SiLU (register halo reuse, 4 rows/thread)
    conv_silu_kernel<<<((ROWS / 4) * (CONV_DIM / 8)) / 256, 256, 0, stream>>>(
        zxb, conv_w, conv_b, xbc);

    // 4. cumsum of dA
    cumsum_kernel<<<BATCH * NC * NHEADS, 256, 0, stream>>>(dtsp, A_log, Acs);

    // 5. chunk states (MFMA)
    states_mfma_kernel<<<BATCH * NC * NHEADS, 256, 0, stream>>>(xbc, dtsp, Acs, states);

    // 6. inter-chunk scan (in place)
    chunkscan_kernel<<<(BATCH * NHEADS * HEADDIM * D_STATE) / 256, 256, 0, stream>>>(
        states, Acs);

    // 7. CB = C @ B^T per (b,c) (MFMA, m97 structure)
    gemm_mfma_bt<float><<<dim3(2, 2, BATCH * NC), 256, 0, stream>>>(
        xbc + D_INNER + D_STATE, xbc + D_INNER, CBm,
        CHUNK, CHUNK, D_STATE, CONV_DIM, CONV_DIM, CHUNK,
        (long long)CHUNK * CONV_DIM, (long long)CHUNK * CONV_DIM, (long long)CHUNK * CHUNK);

    // 8. Y (MFMA): diag + off
    y_mfma_kernel<<<BATCH * NC * NHEADS, 256, 0, stream>>>(xbc, dtsp, Acs, CBm, states, Y);

    // 9. gate + RMSNorm
    gate_norm_kernel<<<ROWS, 256, 0, stream>>>(Y, zxb, xbc, Dv, norm_w);

    // 10. out-projection: 128x128 counted-vmcnt MFMA (grid 64x8 = 512 = 2*256)
    gemm128c_mfma_bt<float><<<(ROWS / 128) * (D_MODEL / 128), 256, 0, stream>>>(
        Y, woutb, out, ROWS, D_MODEL, D_INNER, D_INNER, D_INNER, D_MODEL, D_MODEL / 128);
}

// Round 14
// 333.372 us; speedup vs baseline: 1.9228x; 1.9228x over previous
//
#include <hip/hip_runtime.h>
#include <hip/hip_bf16.h>
#include <cstddef>
#include <cstdint>

#define D_MODEL     1024
#define D_INNER     2048
#define D_STATE     128
#define NHEADS      16
#define HEADDIM     128
#define D_CONV      4
#define CHUNK       256
#define CONV_DIM    2304      // D_INNER + 2*D_STATE
#define DIM_IN_PROJ 4368      // 2*D_INNER + 2*D_STATE + NHEADS
#define NPAD_WIN    4608      // 18*256 = 36*128, zero-padded W_in rows
#define BATCH       2
#define SEQ         4096
#define ROWS        8192      // BATCH*SEQ
#define NC          16        // SEQ/CHUNK
#define EPS         1e-5f

typedef __hip_bfloat16 bf16;
typedef __attribute__((ext_vector_type(8))) short bf16x8;
typedef __attribute__((ext_vector_type(4))) float f32x4;

__device__ __forceinline__ float sigmoidf_(float x) { return 1.f / (1.f + expf(-x)); }

__device__ __forceinline__ float ldf(const float* p) { return *p; }
__device__ __forceinline__ float ldf(const bf16* p)  { return __bfloat162float(*p); }
__device__ __forceinline__ void  stf(float* p, float v) { *p = v; }
__device__ __forceinline__ void  stf(bf16* p, float v)  { *p = __float2bfloat16(v); }

__device__ __forceinline__ short f2bs(float x) {
    bf16 h = __float2bfloat16(x);
    return __builtin_bit_cast(short, h);
}
__device__ __forceinline__ float bs2f(short s) {
    unsigned int u = ((unsigned int)(unsigned short)s) << 16;
    return __builtin_bit_cast(float, u);
}

#define GLOAD_LDS16(gp, lp) \
    __builtin_amdgcn_global_load_lds((const __attribute__((address_space(1))) unsigned int*)(gp), \
        (__attribute__((address_space(3))) unsigned int*)(lp), 16, 0, 0)

// ===========================================================================
// 128x256 bf16 GEMM: C = A[M][K] * B[N][K]^T — round-12 known-good config.
// 256 threads = 4 column-waves; each wave owns 128x64 output (acc[8][4]).
// BK=32; LDS = [2buf](A:128x32 + B:256x32) = 48 KB.
// __launch_bounds__(256, 2): DO NOT raise to 3 — acc[8][4] needs ~128
// accumulator regs on top of ~104 arch VGPRs; a 3-wave bound forces the
// allocator to spill accumulators to scratch (round-13: FETCH 117->503 MB,
// MfmaUtil 32->6.7%, 4.5x slower).
// Per K-tile: VMW0 (drains stage(t), issued one full phase earlier) -> BAR
// -> 12 ds_read -> stage(t+1) into buf^1 -> 32 MFMA (setprio).
// Grid: (M/128)*(N/256), %8==0 for bijective XCD swizzle.
// Requires: M%128==0, K%32==0, B rows valid up to col0+255 (pad B).
// ===========================================================================
__global__ __launch_bounds__(256, 2) void gemm128x256_mfma_bt(
    const bf16* __restrict__ A, const bf16* __restrict__ B, bf16* __restrict__ C,
    int M, int N, int K, int lda, int ldb, int ldc, int gx)
{
    __shared__ bf16 As[2][128 * 32];   // 16 KB
    __shared__ bf16 Bs[2][256 * 32];   // 32 KB

    const int tid  = threadIdx.x;
    const int lane = tid & 63;
    const int wave = tid >> 6;           // 0..3 : column quarter
    const int l15  = lane & 15;
    const int l4   = lane >> 4;

    // bijective XCD-chunked swizzle (grid % 8 == 0)
    const int cpx  = (int)gridDim.x >> 3;
    const int wg   = ((int)blockIdx.x & 7) * cpx + ((int)blockIdx.x >> 3);
    const int row0 = (wg / gx) * 128;
    const int col0 = (wg % gx) * 256;

    const int NT = K >> 5;

    f32x4 acc[8][4];
#pragma unroll
    for (int m = 0; m < 8; m++)
#pragma unroll
        for (int n = 0; n < 4; n++) acc[m][n] = (f32x4){0.f, 0.f, 0.f, 0.f};

#define BAR_()  { asm volatile("" ::: "memory"); __builtin_amdgcn_s_barrier(); asm volatile("" ::: "memory"); }
#define VMW0_() asm volatile("s_waitcnt vmcnt(0)" ::: "memory")

    auto STAGE_A = [&](int kt, int buf) {
#pragma unroll
        for (int sw = 0; sw < 2; sw++) {
            int s  = sw * 256 + tid;             // 0..511
            int r  = s >> 2;                     // 0..127
            int cg = (s & 3) ^ ((r >> 1) & 3);   // source pre-swizzle
            const bf16* src = A + (size_t)(row0 + r) * lda + kt * 32 + cg * 8;
            GLOAD_LDS16(src, &As[buf][s * 8]);   // linear dest
        }
    };
    auto STAGE_B = [&](int kt, int buf) {
#pragma unroll
        for (int sw = 0; sw < 4; sw++) {
            int s  = sw * 256 + tid;             // 0..1023
            int r  = s >> 2;                     // 0..255
            int cg = (s & 3) ^ ((r >> 1) & 3);
            const bf16* src = B + (size_t)(col0 + r) * ldb + kt * 32 + cg * 8;
            GLOAD_LDS16(src, &Bs[buf][s * 8]);
        }
    };
    auto LOADA = [&](int buf, bf16x8* af) {
#pragma unroll
        for (int i = 0; i < 8; i++) {
            int r = i * 16 + l15;
            af[i] = *reinterpret_cast<const bf16x8*>(
                &As[buf][r * 32 + ((l4 ^ ((r >> 1) & 3)) << 3)]);
        }
    };
    auto LOADB = [&](int buf, bf16x8* bb) {
#pragma unroll
        for (int n = 0; n < 4; n++) {
            int r = wave * 64 + n * 16 + l15;
            bb[n] = *reinterpret_cast<const bf16x8*>(
                &Bs[buf][r * 32 + ((l4 ^ ((r >> 1) & 3)) << 3)]);
        }
    };
    auto MFMAQ = [&](bf16x8* af, bf16x8* bb) {
        __builtin_amdgcn_s_setprio(1);
#pragma unroll
        for (int i = 0; i < 8; i++)
#pragma unroll
            for (int n = 0; n < 4; n++)
                acc[i][n] = __builtin_amdgcn_mfma_f32_16x16x32_bf16(
                    af[i], bb[n], acc[i][n], 0, 0, 0);
        __builtin_amdgcn_s_setprio(0);
    };

    // prologue: stage tile 0 fully
    STAGE_A(0, 0); STAGE_B(0, 0);

    bf16x8 af[8], bb[4];
    for (int t = 0; t < NT; t++) {
        const int buf = t & 1;
        VMW0_();                 // drain stage(t) (issued a full phase ago)
        BAR_();                  // publish to all waves
        LOADA(buf, af);
        LOADB(buf, bb);
        if (t + 1 < NT) {        // stage next tile into the opposite buffer
            STAGE_A(t + 1, buf ^ 1);
            STAGE_B(t + 1, buf ^ 1);
        }
        MFMAQ(af, bb);
    }

    // epilogue
#pragma unroll
    for (int m = 0; m < 8; m++) {
        int gr = row0 + m * 16 + l4 * 4;
#pragma unroll
        for (int n = 0; n < 4; n++) {
            int gc = col0 + wave * 64 + n * 16 + l15;
            if (gc < N) {
#pragma unroll
                for (int j = 0; j < 4; j++)
                    stf(&C[(size_t)(gr + j) * ldc + gc], acc[m][n][j]);
            }
        }
    }
#undef BAR_
#undef VMW0_
}

// ===========================================================================
// 128x128 bf16 GEMM: counted-vmcnt kk-split (best for the skinny out-proj)
// ===========================================================================
template<typename TC>
__global__ __launch_bounds__(256, 2) void gemm128c_mfma_bt(
    const bf16* __restrict__ A, const bf16* __restrict__ B, TC* __restrict__ C,
    int M, int N, int K, int lda, int ldb, int ldc, int gx)
{
    __shared__ bf16 As[2][2][128 * 32];
    __shared__ bf16 Bs[2][2][128 * 32];

    const int tid  = threadIdx.x;
    const int lane = tid & 63;
    const int wave = tid >> 6;
    const int wm   = wave >> 1;
    const int wn   = wave & 1;
    const int l15  = lane & 15;
    const int l4   = lane >> 4;

    const int cpx  = (int)gridDim.x >> 3;
    const int wg   = ((int)blockIdx.x & 7) * cpx + ((int)blockIdx.x >> 3);
    const int row0 = (wg / gx) * 128;
    const int col0 = (wg % gx) * 128;

    const int NT = K >> 6;

    f32x4 acc[4][4];
#pragma unroll
    for (int m = 0; m < 4; m++)
#pragma unroll
        for (int n = 0; n < 4; n++) acc[m][n] = (f32x4){0.f, 0.f, 0.f, 0.f};

#define BAR_()  { asm volatile("" ::: "memory"); __builtin_amdgcn_s_barrier(); asm volatile("" ::: "memory"); }
#define VMW0_() asm volatile("s_waitcnt vmcnt(0)" ::: "memory")
#define VMW4_() asm volatile("s_waitcnt vmcnt(4)" ::: "memory")

    auto STAGE_A = [&](int kt, int buf, int kk) {
#pragma unroll
        for (int sw = 0; sw < 2; sw++) {
            int s  = sw * 256 + tid;
            int r  = s >> 2;
            int cg = (s & 3) ^ ((r >> 1) & 3);
            const bf16* src = A + (size_t)(row0 + r) * lda + kt * 64 + kk * 32 + cg * 8;
            GLOAD_LDS16(src, &As[buf][kk][s * 8]);
        }
    };
    auto STAGE_B = [&](int kt, int buf, int kk) {
#pragma unroll
        for (int sw = 0; sw < 2; sw++) {
            int s  = sw * 256 + tid;
            int r  = s >> 2;
            int cg = (s & 3) ^ ((r >> 1) & 3);
            const bf16* src = B + (size_t)(col0 + r) * ldb + kt * 64 + kk * 32 + cg * 8;
            GLOAD_LDS16(src, &Bs[buf][kk][s * 8]);
        }
    };
    auto LOADA = [&](int buf, int kk, bf16x8* af) {
#pragma unroll
        for (int i = 0; i < 4; i++) {
            int r = wm * 64 + i * 16 + l15;
            af[i] = *reinterpret_cast<const bf16x8*>(
                &As[buf][kk][r * 32 + ((l4 ^ ((r >> 1) & 3)) << 3)]);
        }
    };
    auto LOADB = [&](int buf, int kk, bf16x8* bb) {
#pragma unroll
        for (int n = 0; n < 4; n++) {
            int r = wn * 64 + n * 16 + l15;
            bb[n] = *reinterpret_cast<const bf16x8*>(
                &Bs[buf][kk][r * 32 + ((l4 ^ ((r >> 1) & 3)) << 3)]);
        }
    };
    auto MFMAQ = [&](bf16x8* af, bf16x8* bb) {
        __builtin_amdgcn_s_setprio(1);
#pragma unroll
        for (int i = 0; i < 4; i++)
#pragma unroll
            for (int n = 0; n < 4; n++)
                acc[i][n] = __builtin_amdgcn_mfma_f32_16x16x32_bf16(
                    af[i], bb[n], acc[i][n], 0, 0, 0);
        __builtin_amdgcn_s_setprio(0);
    };

    STAGE_A(0, 0, 0); STAGE_B(0, 0, 0);
    STAGE_A(0, 0, 1); STAGE_B(0, 0, 1);
    VMW0_();
    BAR_();

    bf16x8 af[4], bb[4];
    for (int t = 0; t < NT; t++) {
        const int buf  = t & 1;
        const int nbuf = buf ^ 1;
        const int nk   = (t + 1 < NT) ? t + 1 : 0;
        LOADA(buf, 0, af);
        LOADB(buf, 0, bb);
        STAGE_A(nk, nbuf, 0);
        STAGE_B(nk, nbuf, 0);
        VMW4_();
        BAR_();
        MFMAQ(af, bb);
        LOADA(buf, 1, af);
        LOADB(buf, 1, bb);
        STAGE_A(nk, nbuf, 1);
        STAGE_B(nk, nbuf, 1);
        VMW4_();
        BAR_();
        MFMAQ(af, bb);
    }

#pragma unroll
    for (int m = 0; m < 4; m++) {
        int gr = row0 + wm * 64 + m * 16 + l4 * 4;
#pragma unroll
        for (int n = 0; n < 4; n++) {
            int gc = col0 + wn * 64 + n * 16 + l15;
            if (gc < N) {
#pragma unroll
                for (int j = 0; j < 4; j++)
                    stf(&C[(size_t)(gr + j) * ldc + gc], acc[m][n][j]);
            }
        }
    }
#undef BAR_
#undef VMW0_
#undef VMW4_
}

// ---------------------------------------------------------------------------
// MFMA bf16 GEMM (m97 structure) — kept for the batched CB GEMM
// ---------------------------------------------------------------------------
template<typename TC>
__global__ __launch_bounds__(256) void gemm_mfma_bt(
    const bf16* __restrict__ A, const bf16* __restrict__ B, TC* __restrict__ C,
    int M, int N, int K, int lda, int ldb, int ldc,
    long long sA, long long sB, long long sC)
{
    A += (long long)blockIdx.z * sA;
    B += (long long)blockIdx.z * sB;
    C += (long long)blockIdx.z * sC;

    __shared__ bf16 As[128 * 32];
    __shared__ bf16 Bs[128 * 32];

    const int tid  = threadIdx.x;
    const int lane = tid & 63;
    const int wave = tid >> 6;
    const int wr   = wave >> 1;
    const int wc   = wave & 1;
    const int row0 = blockIdx.y * 128;
    const int col0 = blockIdx.x * 128;
    const int l15  = lane & 15;
    const int l4   = lane >> 4;

    const int srow = tid >> 2;
    const int scol = (tid & 3) * 8;

    f32x4 acc[4][4];
#pragma unroll
    for (int m = 0; m < 4; m++)
#pragma unroll
        for (int n = 0; n < 4; n++) acc[m][n] = (f32x4){0.f, 0.f, 0.f, 0.f};

    for (int k0 = 0; k0 < K; k0 += 32) {
        const bf16* gA0 = A + (size_t)(row0 + srow) * lda + k0 + scol;
        const bf16* gA1 = A + (size_t)(row0 + 64 + srow) * lda + k0 + scol;
        const bf16* gB0 = B + (size_t)(col0 + srow) * ldb + k0 + scol;
        const bf16* gB1 = B + (size_t)(col0 + 64 + srow) * ldb + k0 + scol;
        GLOAD_LDS16(gA0, &As[tid * 8]);
        GLOAD_LDS16(gA1, &As[2048 + tid * 8]);
        GLOAD_LDS16(gB0, &Bs[tid * 8]);
        GLOAD_LDS16(gB1, &Bs[2048 + tid * 8]);
        __syncthreads();

        bf16x8 af[4], bg[4];
#pragma unroll
        for (int m = 0; m < 4; m++) {
            int r = wr * 64 + m * 16 + l15;
            af[m] = *reinterpret_cast<const bf16x8*>(&As[r * 32 + l4 * 8]);
        }
#pragma unroll
        for (int n = 0; n < 4; n++) {
            int r = wc * 64 + n * 16 + l15;
            bg[n] = *reinterpret_cast<const bf16x8*>(&Bs[r * 32 + l4 * 8]);
        }
#pragma unroll
        for (int m = 0; m < 4; m++)
#pragma unroll
            for (int n = 0; n < 4; n++)
                acc[m][n] = __builtin_amdgcn_mfma_f32_16x16x32_bf16(af[m], bg[n], acc[m][n], 0, 0, 0);
        __syncthreads();
    }

#pragma unroll
    for (int m = 0; m < 4; m++) {
        int grb = row0 + wr * 64 + m * 16 + l4 * 4;
#pragma unroll
        for (int n = 0; n < 4; n++) {
            int gc = col0 + wc * 64 + n * 16 + l15;
            if (gc < N) {
#pragma unroll
                for (int j = 0; j < 4; j++) {
                    int gr = grb + j;
                    if (gr < M) stf(&C[(size_t)gr * ldc + gc], acc[m][n][j]);
                }
            }
        }
    }
}

// ---------------------------------------------------------------------------
// dt projection + softplus + bf16 cast of u, fused. One wave per row.
// ---------------------------------------------------------------------------
__global__ __launch_bounds__(256) void dt_proj_kernel(
    const float* __restrict__ u, const float* __restrict__ Wdt,
    const float* __restrict__ dt_bias, float* __restrict__ dtsp,
    ushort* __restrict__ ub)
{
    const int wave = threadIdx.x >> 6;
    const int lane = threadIdx.x & 63;
    const int row  = blockIdx.x * 4 + wave;
    const float* urow = u + (size_t)row * D_MODEL;

    float4 uv[4];
#pragma unroll
    for (int w = 0; w < 4; w++)
        uv[w] = *reinterpret_cast<const float4*>(&urow[lane * 4 + w * 256]);

#pragma unroll
    for (int w = 0; w < 4; w++) {
        ushort4 o;
        o.x = (unsigned short)f2bs(uv[w].x);
        o.y = (unsigned short)f2bs(uv[w].y);
        o.z = (unsigned short)f2bs(uv[w].z);
        o.w = (unsigned short)f2bs(uv[w].w);
        *reinterpret_cast<ushort4*>(&ub[(size_t)row * D_MODEL + lane * 4 + w * 256]) = o;
    }

    float acc[NHEADS];
#pragma unroll
    for (int h = 0; h < NHEADS; h++) acc[h] = 0.f;
#pragma unroll
    for (int w = 0; w < 4; w++) {
#pragma unroll
        for (int h = 0; h < NHEADS; h++) {
            float4 wv = *reinterpret_cast<const float4*>(&Wdt[(size_t)h * D_MODEL + lane * 4 + w * 256]);
            acc[h] += uv[w].x * wv.x + uv[w].y * wv.y + uv[w].z * wv.z + uv[w].w * wv.w;
        }
    }
#pragma unroll
    for (int h = 0; h < NHEADS; h++)
#pragma unroll
        for (int off = 32; off > 0; off >>= 1)
            acc[h] += __shfl_xor(acc[h], off, 64);

    float sel = 0.f;
#pragma unroll
    for (int h = 0; h < NHEADS; h++) sel = (lane == h) ? acc[h] : sel;
    if (lane < NHEADS) {
        float x = sel + dt_bias[lane];
        dtsp[(size_t)row * NHEADS + lane] = (x > 20.f) ? x : log1pf(expf(x));
    }
}

// ---------------------------------------------------------------------------
// casts (weights)
// ---------------------------------------------------------------------------
__global__ __launch_bounds__(256) void cast_bf16_kernel(
    const float4* __restrict__ src, ushort4* __restrict__ dst, int n4)
{
    int i = blockIdx.x * 256 + threadIdx.x;
    if (i >= n4) return;
    float4 v = src[i];
    ushort4 o;
    o.x = (unsigned short)f2bs(v.x);
    o.y = (unsigned short)f2bs(v.y);
    o.z = (unsigned short)f2bs(v.z);
    o.w = (unsigned short)f2bs(v.w);
    dst[i] = o;
}

__global__ __launch_bounds__(256) void cast_win_kernel(
    const float4* __restrict__ src, ushort4* __restrict__ dst)
{
    int i = blockIdx.x * 256 + threadIdx.x;
    if (i >= NPAD_WIN * D_MODEL / 4) return;
    int row = (i * 4) / D_MODEL;
    ushort4 o = {0, 0, 0, 0};
    if (row < DIM_IN_PROJ) {
        float4 v = src[i];
        o.x = (unsigned short)f2bs(v.x);
        o.y = (unsigned short)f2bs(v.y);
        o.z = (unsigned short)f2bs(v.z);
        o.w = (unsigned short)f2bs(v.w);
    }
    dst[i] = o;
}

// ---------------------------------------------------------------------------
// Depthwise causal conv (width 4) + bias + SiLU — register halo reuse:
// each thread computes 4 consecutive rows x 8 channels from 7 row-vectors.
// ---------------------------------------------------------------------------
__global__ __launch_bounds__(256) void conv_silu_kernel(
    const bf16* __restrict__ zx, const float* __restrict__ cw,
    const float* __restrict__ cb, bf16* __restrict__ xbc)
{
    const int CW = CONV_DIM / 8;               // 288
    int idx = blockIdx.x * 256 + threadIdx.x;  // over (ROWS/4) * CW
    if (idx >= (ROWS / 4) * CW) return;
    int c8   = idx % CW;
    int r4   = idx / CW;
    int c0   = c8 * 8;
    int row0 = r4 * 4;
    int l0   = row0 & (SEQ - 1);

    float vr[7][8];
#pragma unroll
    for (int k = 0; k < 7; k++) {
        int ls = l0 - 3 + k;
        if (ls < 0) {
#pragma unroll
            for (int j = 0; j < 8; j++) vr[k][j] = 0.f;
        } else {
            bf16x8 v = *reinterpret_cast<const bf16x8*>(
                zx + (size_t)(row0 - 3 + k) * DIM_IN_PROJ + D_INNER + c0);
#pragma unroll
            for (int j = 0; j < 8; j++) vr[k][j] = bs2f(v[j]);
        }
    }

    float4 t[8];
#pragma unroll
    for (int j = 0; j < 8; j++)
        t[j] = *reinterpret_cast<const float4*>(&cw[(size_t)(c0 + j) * D_CONV]);
    float bias[8];
    {
        float4 b0 = *reinterpret_cast<const float4*>(&cb[c0]);
        float4 b1 = *reinterpret_cast<const float4*>(&cb[c0 + 4]);
        bias[0] = b0.x; bias[1] = b0.y; bias[2] = b0.z; bias[3] = b0.w;
        bias[4] = b1.x; bias[5] = b1.y; bias[6] = b1.z; bias[7] = b1.w;
    }

#pragma unroll
    for (int r = 0; r < 4; r++) {
        float acc[8];
#pragma unroll
        for (int j = 0; j < 8; j++) acc[j] = bias[j];
#pragma unroll
        for (int k = 0; k < D_CONV; k++) {
#pragma unroll
            for (int j = 0; j < 8; j++) {
                float tap = (k == 0) ? t[j].x : (k == 1) ? t[j].y : (k == 2) ? t[j].z : t[j].w;
                acc[j] += tap * vr[r + k][j];
            }
        }
        bf16x8 o;
#pragma unroll
        for (int j = 0; j < 8; j++) {
            float x = acc[j];
            o[j] = f2bs(x * sigmoidf_(x));
        }
        *reinterpret_cast<bf16x8*>(&xbc[(size_t)(row0 + r) * CONV_DIM + c0]) = o;
    }
}

// ---------------------------------------------------------------------------
__global__ __launch_bounds__(256) void cumsum_kernel(
    const float* __restrict__ dtsp, const float* __restrict__ A_log,
    float* __restrict__ Acs)
{
    int blk = blockIdx.x;
    int h   = blk % NHEADS;
    int bc  = blk / NHEADS;
    int t   = threadIdx.x;
    int row = bc * CHUNK + t;
    float A = -expf(A_log[h]);
    __shared__ float buf[CHUNK];
    buf[t] = dtsp[(size_t)row * NHEADS + h] * A;
    __syncthreads();
    for (int off = 1; off < CHUNK; off <<= 1) {
        float v = (t >= off) ? buf[t - off] : 0.f;
        __syncthreads();
        buf[t] += v;
        __syncthreads();
    }
    Acs[(size_t)blk * CHUNK + t] = buf[t];
}

// ---------------------------------------------------------------------------
// states (MFMA): states[p][n] = sum_q xg[q,p] * B[q,n]
// ---------------------------------------------------------------------------
__global__ __launch_bounds__(256, 2) void states_mfma_kernel(
    const bf16* __restrict__ xbc, const float* __restrict__ dtsp,
    const float* __restrict__ Acs, float* __restrict__ states)
{
    const int bch  = blockIdx.x;
    const int h    = bch % NHEADS;
    const int bc   = bch / NHEADS;
    const int row0 = bc * CHUNK;
    const int tid  = threadIdx.x;
    const int lane = tid & 63;
    const int wave = tid >> 6;
    const int l15  = lane & 15;
    const int l4   = lane >> 4;

    __shared__ float g[CHUNK];
    __shared__ bf16 xT[128 * 32];
    __shared__ bf16 bT[128 * 32];

    {
        float last = Acs[(size_t)bch * CHUNK + CHUNK - 1];
        float a    = Acs[(size_t)bch * CHUNK + tid];
        g[tid] = dtsp[(size_t)(row0 + tid) * NHEADS + h] * __expf(last - a);
    }

    const int sp0 = (tid & 15) * 8;
    const int ssl = 2 * (tid >> 4);

    f32x4 acc[2][8];
#pragma unroll
    for (int m = 0; m < 2; m++)
#pragma unroll
        for (int n = 0; n < 8; n++) acc[m][n] = (f32x4){0.f, 0.f, 0.f, 0.f};

    for (int q0 = 0; q0 < CHUNK; q0 += 32) {
        __syncthreads();
        {
            const bf16* gx = xbc + (size_t)(row0 + q0 + ssl) * CONV_DIM + h * HEADDIM + sp0;
            bf16x8 v0 = *reinterpret_cast<const bf16x8*>(gx);
            bf16x8 v1 = *reinterpret_cast<const bf16x8*>(gx + CONV_DIM);
            const bf16* gb = xbc + (size_t)(row0 + q0 + ssl) * CONV_DIM + D_INNER + sp0;
            bf16x8 w0 = *reinterpret_cast<const bf16x8*>(gb);
            bf16x8 w1 = *reinterpret_cast<const bf16x8*>(gb + CONV_DIM);
            float g0 = g[q0 + ssl], g1 = g[q0 + ssl + 1];
#pragma unroll
            for (int j = 0; j < 8; j++) {
                unsigned int px = (unsigned short)f2bs(bs2f(v0[j]) * g0) |
                                  ((unsigned int)(unsigned short)f2bs(bs2f(v1[j]) * g1) << 16);
                *reinterpret_cast<unsigned int*>(&xT[(sp0 + j) * 32 + ssl]) = px;
                unsigned int pb = (unsigned short)w0[j] |
                                  ((unsigned int)(unsigned short)w1[j] << 16);
                *reinterpret_cast<unsigned int*>(&bT[(sp0 + j) * 32 + ssl]) = pb;
            }
        }
        __syncthreads();

        bf16x8 af[2], bg[8];
#pragma unroll
        for (int m = 0; m < 2; m++) {
            int p = wave * 32 + m * 16 + l15;
            af[m] = *reinterpret_cast<const bf16x8*>(&xT[p * 32 + l4 * 8]);
        }
#pragma unroll
        for (int n = 0; n < 8; n++) {
            int nn = n * 16 + l15;
            bg[n] = *reinterpret_cast<const bf16x8*>(&bT[nn * 32 + l4 * 8]);
        }
#pragma unroll
        for (int m = 0; m < 2; m++)
#pragma unroll
            for (int n = 0; n < 8; n++)
                acc[m][n] = __builtin_amdgcn_mfma_f32_16x16x32_bf16(af[m], bg[n], acc[m][n], 0, 0, 0);
    }

    float* sp = states + (size_t)bch * HEADDIM * D_STATE;
#pragma unroll
    for (int m = 0; m < 2; m++) {
        int pb = wave * 32 + m * 16 + l4 * 4;
#pragma unroll
        for (int n = 0; n < 8; n++) {
            int nn = n * 16 + l15;
#pragma unroll
            for (int j = 0; j < 4; j++)
                sp[(size_t)(pb + j) * D_STATE + nn] = acc[m][n][j];
        }
    }
}

// ---------------------------------------------------------------------------
// Sequential inter-chunk scan, IN PLACE on states
// ---------------------------------------------------------------------------
__global__ __launch_bounds__(256) void chunkscan_kernel(
    float* __restrict__ states, const float* __restrict__ Acs)
{
    int idx = blockIdx.x * 256 + threadIdx.x;
    int pn  = idx % (HEADDIM * D_STATE);
    int bh  = idx / (HEADDIM * D_STATE);
    int h   = bh % NHEADS;
    int b   = bh / NHEADS;
    float carry = 0.f;
    for (int c = 0; c < NC; c++) {
        int bch = (b * NC + c) * NHEADS + h;
        size_t off = (size_t)bch * HEADDIM * D_STATE + pn;
        float s   = states[off];
        states[off] = carry;
        float dec = expf(Acs[(size_t)bch * CHUNK + CHUNK - 1]);
        carry = carry * dec + s;
    }
}

// ---------------------------------------------------------------------------
// Y (MFMA): diag (causal, CB*L) + off (prev-state) per (b,c,h)
// ---------------------------------------------------------------------------
__global__ __launch_bounds__(256, 2) void y_mfma_kernel(
    const bf16* __restrict__ xbc, const float* __restrict__ dtsp,
    const float* __restrict__ Acs, const float* __restrict__ CBm,
    const float* __restrict__ prev, bf16* __restrict__ Y)
{
    const int bch  = blockIdx.x;
    const int h    = bch % NHEADS;
    const int bc   = bch / NHEADS;
    const int row0 = bc * CHUNK;
    const int tid  = threadIdx.x;
    const int lane = tid & 63;
    const int wave = tid >> 6;
    const int l15  = lane & 15;
    const int l4   = lane >> 4;

    __shared__ float sAcs[CHUNK];
    __shared__ float sdt[CHUNK];
    __shared__ bf16 xT[128 * 32];

    sAcs[tid] = Acs[(size_t)bch * CHUNK + tid];
    sdt[tid]  = dtsp[(size_t)(row0 + tid) * NHEADS + h];
    __syncthreads();

    int qb[4]; float aq[4];
#pragma unroll
    for (int m = 0; m < 4; m++) {
        qb[m] = (m * 4 + wave) * 16;
        aq[m] = sAcs[qb[m] + l15];
    }

    f32x4 acc[4][8];
#pragma unroll
    for (int m = 0; m < 4; m++)
#pragma unroll
        for (int n = 0; n < 8; n++) acc[m][n] = (f32x4){0.f, 0.f, 0.f, 0.f};

    const int sp0 = (tid & 15) * 8;
    const int ssl = 2 * (tid >> 4);

    // ---------------- diag phase ----------------
    for (int s0 = 0; s0 < CHUNK; s0 += 32) {
        __syncthreads();
        {
            const bf16* gx = xbc + (size_t)(row0 + s0 + ssl) * CONV_DIM + h * HEADDIM + sp0;
            bf16x8 v0 = *reinterpret_cast<const bf16x8*>(gx);
            bf16x8 v1 = *reinterpret_cast<const bf16x8*>(gx + CONV_DIM);
            float d0 = sdt[s0 + ssl], d1 = sdt[s0 + ssl + 1];
#pragma unroll
            for (int j = 0; j < 8; j++) {
                unsigned int px = (unsigned short)f2bs(bs2f(v0[j]) * d0) |
                                  ((unsigned int)(unsigned short)f2bs(bs2f(v1[j]) * d1) << 16);
                *reinterpret_cast<unsigned int*>(&xT[(sp0 + j) * 32 + ssl]) = px;
            }
        }
        __syncthreads();

        bf16x8 bg[8];
#pragma unroll
        for (int n = 0; n < 8; n++)
            bg[n] = *reinterpret_cast<const bf16x8*>(&xT[(n * 16 + l15) * 32 + l4 * 8]);

        f32x4 as0 = *reinterpret_cast<const f32x4*>(&sAcs[s0 + l4 * 8]);
        f32x4 as1 = *reinterpret_cast<const f32x4*>(&sAcs[s0 + l4 * 8 + 4]);

#pragma unroll
        for (int m = 0; m < 4; m++) {
            if (s0 >= qb[m] + 16) continue;
            int q = qb[m] + l15;
            const float* cbp = CBm + ((size_t)bc * CHUNK + q) * CHUNK + s0 + l4 * 8;
            f32x4 c0 = *reinterpret_cast<const f32x4*>(cbp);
            f32x4 c1 = *reinterpret_cast<const f32x4*>(cbp + 4);
            bf16x8 af;
#pragma unroll
            for (int j = 0; j < 8; j++) {
                int s = s0 + l4 * 8 + j;
                float cb = (j < 4) ? c0[j] : c1[j - 4];
                float a  = (j < 4) ? as0[j] : as1[j - 4];
                float w  = (s <= q) ? cb * __expf(aq[m] - a) : 0.f;
                af[j] = f2bs(w);
            }
#pragma unroll
            for (int n = 0; n < 8; n++)
                acc[m][n] = __builtin_amdgcn_mfma_f32_16x16x32_bf16(af, bg[n], acc[m][n], 0, 0, 0);
        }
    }

    // ---------------- off (prev-state) phase ----------------
    float eaq[4];
#pragma unroll
    for (int m = 0; m < 4; m++) eaq[m] = __expf(aq[m]);

    const float* prevh = prev + (size_t)bch * HEADDIM * D_STATE;
    for (int n0 = 0; n0 < D_STATE; n0 += 32) {
        bf16x8 bg[8];
#pragma unroll
        for (int n = 0; n < 8; n++) {
            const float* pr = prevh + (size_t)(n * 16 + l15) * D_STATE + n0 + l4 * 8;
            f32x4 u0 = *reinterpret_cast<const f32x4*>(pr);
            f32x4 u1 = *reinterpret_cast<const f32x4*>(pr + 4);
            bf16x8 b;
#pragma unroll
            for (int j = 0; j < 4; j++) { b[j] = f2bs(u0[j]); b[4 + j] = f2bs(u1[j]); }
            bg[n] = b;
        }
#pragma unroll
        for (int m = 0; m < 4; m++) {
            const bf16* crow = xbc + (size_t)(row0 + qb[m] + l15) * CONV_DIM
                             + D_INNER + D_STATE + n0 + l4 * 8;
            bf16x8 cv = *reinterpret_cast<const bf16x8*>(crow);
            bf16x8 af;
#pragma unroll
            for (int j = 0; j < 8; j++) af[j] = f2bs(bs2f(cv[j]) * eaq[m]);
#pragma unroll
            for (int n = 0; n < 8; n++)
                acc[m][n] = __builtin_amdgcn_mfma_f32_16x16x32_bf16(af, bg[n], acc[m][n], 0, 0, 0);
        }
    }

    // ---------------- write Y ----------------
#pragma unroll
    for (int m = 0; m < 4; m++) {
        int qrb = qb[m] + l4 * 4;
#pragma unroll
        for (int n = 0; n < 8; n++) {
            int p = n * 16 + l15;
#pragma unroll
            for (int j = 0; j < 4; j++)
                stf(&Y[(size_t)(row0 + qrb + j) * D_INNER + h * HEADDIM + p], acc[m][n][j]);
        }
    }
}

// ---------------------------------------------------------------------------
// y = (Y + D*x) * silu(z);  RMSNorm; in-place on Y (bf16) — vectorized
// ---------------------------------------------------------------------------
__global__ __launch_bounds__(256) void gate_norm_kernel(
    bf16* __restrict__ Yio, const bf16* __restrict__ zx,
    const bf16* __restrict__ xbc, const float* __restrict__ Dv,
    const float* __restrict__ nw)
{
    int row = blockIdx.x;
    int t   = threadIdx.x;
    int d0  = t * 8;

    bf16x8 yv = *reinterpret_cast<const bf16x8*>(&Yio[(size_t)row * D_INNER + d0]);
    bf16x8 xv = *reinterpret_cast<const bf16x8*>(&xbc[(size_t)row * CONV_DIM + d0]);
    bf16x8 zv = *reinterpret_cast<const bf16x8*>(&zx[(size_t)row * DIM_IN_PROJ + d0]);
    float Dh = Dv[d0 >> 7];

    float vals[8];
    float ss = 0.f;
#pragma unroll
    for (int j = 0; j < 8; j++) {
        float y = bs2f(yv[j]) + Dh * bs2f(xv[j]);
        float z = bs2f(zv[j]);
        y *= z * sigmoidf_(z);
        vals[j] = y;
        ss += y * y;
    }
    __shared__ float red[256];
    red[t] = ss;
    __syncthreads();
    for (int o = 128; o > 0; o >>= 1) {
        if (t < o) red[t] += red[t + o];
        __syncthreads();
    }
    float rms = rsqrtf(red[0] / (float)D_INNER + EPS);

    float4 w0 = *reinterpret_cast<const float4*>(&nw[d0]);
    float4 w1 = *reinterpret_cast<const float4*>(&nw[d0 + 4]);
    bf16x8 o;
    o[0] = f2bs(vals[0] * rms * w0.x);
    o[1] = f2bs(vals[1] * rms * w0.y);
    o[2] = f2bs(vals[2] * rms * w0.z);
    o[3] = f2bs(vals[3] * rms * w0.w);
    o[4] = f2bs(vals[4] * rms * w1.x);
    o[5] = f2bs(vals[5] * rms * w1.y);
    o[6] = f2bs(vals[6] * rms * w1.z);
    o[7] = f2bs(vals[7] * rms * w1.w);
    *reinterpret_cast<bf16x8*>(&Yio[(size_t)row * D_INNER + d0]) = o;
}

// ---------------------------------------------------------------------------
extern "C" void kernel_launch(void* const* d_in, const int* in_sizes, int n_in,
                              void* d_out, int out_size, void* d_ws, size_t ws_size,
                              hipStream_t stream)
{
    const float* u       = (const float*)d_in[0];
    const float* W_in    = (const float*)d_in[1];
    const float* conv_w  = (const float*)d_in[2];
    const float* conv_b  = (const float*)d_in[3];
    const float* dt_bias = (const float*)d_in[4];
    const float* A_log   = (const float*)d_in[5];
    const float* Dv      = (const float*)d_in[6];
    const float* norm_w  = (const float*)d_in[7];
    const float* W_out   = (const float*)d_in[8];
    float* out = (float*)d_out;

    char* base = (char*)d_ws;
    size_t off = 0;
    auto alloc = [&](size_t bytes) -> char* {
        char* p = base + off;
        off += (bytes + 255) & ~(size_t)255;
        return p;
    };
    bf16*  zxb    = (bf16*) alloc((size_t)ROWS * DIM_IN_PROJ * 2);                      // 71.5 MB
    bf16*  xbc    = (bf16*) alloc((size_t)ROWS * CONV_DIM * 2);                         // 37.7 MB
    float* dtsp   = (float*)alloc((size_t)ROWS * NHEADS * 4);
    float* Acs    = (float*)alloc((size_t)BATCH * NC * NHEADS * CHUNK * 4);
    float* states = (float*)alloc((size_t)BATCH * NC * NHEADS * HEADDIM * D_STATE * 4); // 33.5 MB
    float* CBm    = (float*)alloc((size_t)BATCH * NC * CHUNK * CHUNK * 4);              //  8.4 MB
    bf16*  Y      = (bf16*) alloc((size_t)ROWS * D_INNER * 2);                          // 33.5 MB
    bf16*  woutb  = (bf16*) alloc((size_t)D_MODEL * D_INNER * 2);                       //  4.2 MB
    bf16*  ub     = Y;                               // aliases: dead once y_mfma runs
    bf16*  winb   = Y + (size_t)ROWS * D_MODEL;      // 4608*1024 bf16 = 9.4 MB
    if (off > ws_size) return;

    // 0. dt projection (fp32) + softplus + u->bf16 cast, fused
    dt_proj_kernel<<<ROWS / 4, 256, 0, stream>>>(
        u, W_in + (size_t)(D_INNER + CONV_DIM) * D_MODEL, dt_bias, dtsp, (ushort*)ub);

    // 0b. weight casts
    cast_win_kernel<<<(NPAD_WIN * D_MODEL / 4 + 255) / 256, 256, 0, stream>>>(
        (const float4*)W_in, (ushort4*)winb);
    cast_bf16_kernel<<<(D_MODEL * D_INNER / 4 + 255) / 256, 256, 0, stream>>>(
        (const float4*)W_out, (ushort4*)woutb, D_MODEL * D_INNER / 4);

    // 1. in-projection: 128x256 2-blocks/CU MFMA (grid 64x18 = 1152, %8==0)
    gemm128x256_mfma_bt<<<(ROWS / 128) * (NPAD_WIN / 256), 256, 0, stream>>>(
        ub, winb, zxb, ROWS, DIM_IN_PROJ, D_MODEL,
        D_MODEL, D_MODEL, DIM_IN_PROJ, NPAD_WIN / 256);

    // 2. conv + SiLU (register halo reuse, 4 rows/thread)
    conv_silu_kernel<<<((ROWS / 4) * (CONV_DIM / 8)) / 256, 256, 0, stream>>>(
        zxb, conv_w, conv_b, xbc);

    // 4. cumsum of dA
    cumsum_kernel<<<BATCH * NC * NHEADS, 256, 0, stream>>>(dtsp, A_log, Acs);

    // 5. chunk states (MFMA)
    states_mfma_kernel<<<BATCH * NC * NHEADS, 256, 0, stream>>>(xbc, dtsp, Acs, states);

    // 6. inter-chunk scan (in place)
    chunkscan_kernel<<<(BATCH * NHEADS * HEADDIM * D_STATE) / 256, 256, 0, stream>>>(
        states, Acs);

    // 7. CB = C @ B^T per (b,c) (MFMA, m97 structure)
    gemm_mfma_bt<float><<<dim3(2, 2, BATCH * NC), 256, 0, stream>>>(
        xbc + D_INNER + D_STATE, xbc + D_INNER, CBm,
        CHUNK, CHUNK, D_STATE, CONV_DIM, CONV_DIM, CHUNK,
        (long long)CHUNK * CONV_DIM, (long long)CHUNK * CONV_DIM, (long long)CHUNK * CHUNK);

    // 8. Y (MFMA): diag + off
    y_mfma_kernel<<<BATCH * NC * NHEADS, 256, 0, stream>>>(xbc, dtsp, Acs, CBm, states, Y);

    // 9. gate + RMSNorm
    gate_norm_kernel<<<ROWS, 256, 0, stream>>>(Y, zxb, xbc, Dv, norm_w);

    // 10. out-projection: 128x128 counted-vmcnt MFMA (grid 64x8 = 512 = 2*256)
    gemm128c_mfma_bt<float><<<(ROWS / 128) * (D_MODEL / 128), 256, 0, stream>>>(
        Y, woutb, out, ROWS, D_MODEL, D_INNER, D_INNER, D_INNER, D_MODEL, D_MODEL / 128);
}